// Round 1
// 209.771 us; speedup vs baseline: 1.0779x; 1.0779x over previous
//
#include <hip/hip_runtime.h>

typedef int v4i __attribute__((ext_vector_type(4)));

#define QMAX 127.0f

// ---- workspace layout ----
// xq  : int8 padded, swizzled [16][66][66 px][5 c5][4 slots][16]
//       slot s of (col,c5) holds logical ci-chunk s ^ ((col>>1)&3)
// wq2 : int8 fragment-order [9][5][20cog][64lane][16]
// bi  : float [320]
#define XQ_BYTES 22302720
#define WQ_BYTES 921600

__device__ __forceinline__ float clampf(float v, float lo, float hi) {
    return fminf(fmaxf(v, lo), hi);
}

// Bit-exact fast round(v/step): reciprocal multiply, exact-division fallback
// only near half-integer boundaries (trigger ~7e-4; 50x error margin).
__device__ __forceinline__ float qround(float v, float step, float inv) {
    float t = v * inv;
    float r = rintf(t);
    float d = fabsf(t - r);
    if (fabsf(d - 0.5f) < fabsf(t) * 1e-5f + 1e-5f)
        r = rintf(v / step);
    return r;
}

__device__ __forceinline__ void gload_lds16(const char* g, char* l) {
    __builtin_amdgcn_global_load_lds(
        (const __attribute__((address_space(1))) void*)g,
        (__attribute__((address_space(3))) void*)l, 16, 0, 0);
}

__device__ __forceinline__ v4i mfma_i8(v4i a, v4i b, v4i c) {
    return __builtin_amdgcn_mfma_i32_16x16x64_i8(a, b, c, 0, 0, 0);
}

// ---------------------------------------------------------------------------
// Fused producer kernel: one launch so x-quant, w-quant, halo-zero and bias
// all co-schedule (they are mutually independent; different bottlenecks
// overlap instead of serializing across 2 launches).
//   blocks [0,1024)    : x quantize (block = (h,b)), long pole -> first
//   blocks [1024,4624) : wq2 quantize (fragment order)
//   blocks [4624,4949) : xq halo zeroing
//   block  4949        : bias requant
// ---------------------------------------------------------------------------
__global__ __launch_bounds__(256) void fused_prep_kernel(
    const float* __restrict__ x, const float* __restrict__ w,
    const float* __restrict__ bias,
    const float* __restrict__ step_x_p, const float* __restrict__ step_w_p,
    const float* __restrict__ step_b_p, const float* __restrict__ shift_p,
    char* __restrict__ xq, char* __restrict__ wq2, float* __restrict__ bi)
{
    __shared__ float F[64 * 65];   // [ci_local][w], stride 65 floats
    const int bid = blockIdx.x;
    const int t = threadIdx.x;

    if (bid < 1024) {
        // ---- x quantize: one block per (h,b); writes row h+1 interior ----
        const int h = bid & 63;
        const int b = bid >> 6;
        const float step = *step_x_p;
        const float inv  = 1.0f / step;
        const int wcol = t >> 2;       // output col-1 (0..63)
        const int cg   = t & 3;        // logical 16-ci chunk within c5
        v4i vals[5];

        for (int c5 = 0; c5 < 5; ++c5) {
            {
                const int r = t >> 4, c = (t & 15) * 4;
                const float* src = x + (((size_t)(b * 320 + c5 * 64) * 64 + h) * 64);
#pragma unroll
                for (int i = 0; i < 4; ++i) {
                    const int row = r + i * 16;
                    *(float4*)&F[row * 65 + c] =
                        *(const float4*)(src + (size_t)row * 4096 + c);
                }
            }
            __syncthreads();
            int dws[4];
#pragma unroll
            for (int j = 0; j < 4; ++j) {
                int word = 0;
#pragma unroll
                for (int k = 0; k < 4; ++k) {
                    float v = F[(cg * 16 + j * 4 + k) * 65 + wcol];
                    int xi = (int)clampf(qround(v, step, inv), -QMAX, QMAX);
                    word |= (xi & 0xFF) << (8 * k);
                }
                dws[j] = word;
            }
            vals[c5] = (v4i){dws[0], dws[1], dws[2], dws[3]};
            __syncthreads();
        }

        const int col = wcol + 1;
        const int key = (col >> 1) & 3;
        char* base = xq + ((size_t)(b * 66 + (h + 1)) * 66 + col) * 320;
#pragma unroll
        for (int c5 = 0; c5 < 5; ++c5)
            *(v4i*)(base + c5 * 64 + (((cg ^ key)) << 4)) = vals[c5];

    } else if (bid < 4624) {
        // ---- weight quantize into MFMA fragment order ----
        const int tid = (bid - 1024) * 256 + t;
        const float step = *step_w_p;
        const float inv  = 1.0f / step;
        const int p    = tid / 102400;
        const int r    = tid - p * 102400;
        const int c5   = r / 20480;
        const int r2   = r - c5 * 20480;
        const int cog  = r2 >> 10;
        const int r3   = r2 & 1023;
        const int lane = r3 >> 4, j = r3 & 15;
        const int co = cog * 16 + (lane & 15);
        const int ci = c5 * 64 + (lane >> 4) * 16 + j;
        float v = w[(size_t)co * 2880 + ci * 9 + p];
        int q = (int)clampf(qround(v, step, inv), -QMAX, QMAX);
        wq2[tid] = (char)q;
    } else if (bid < 4949) {
        // ---- halo zeroing ----
        int tid = (bid - 4624) * 256 + t;
        if (tid < 83200) {
            int b = tid / 5200;
            int r = tid - b * 5200;
            int px = r / 20;
            int ck = (r - px * 20) * 16;
            int row, col;
            if (px < 66)       { row = 0;  col = px; }
            else if (px < 132) { row = 65; col = px - 66; }
            else { int e = px - 132; row = 1 + (e >> 1); col = (e & 1) * 65; }
            size_t off = ((size_t)(b * 66 + row) * 66 + col) * 320 + ck;
            v4i z = {0, 0, 0, 0};
            *(v4i*)&xq[off] = z;
        }
    } else {
        // ---- bias requant ----
        const float step_b = *step_b_p;
        const float xs = 1.0f / *step_x_p;
        const float ws = 1.0f / *step_w_p;
        const float shift = *shift_p;
#pragma unroll
        for (int co = t; co < 320; co += 256) {
            float b_deq = clampf(rintf(bias[co] / step_b), -QMAX, QMAX) * step_b;
            float v = ((b_deq * shift) * xs) * ws;
            bi[co] = clampf(rintf(v), -QMAX, QMAX);
        }
    }
}

// ---------------------------------------------------------------------------
// Implicit-GEMM conv, v_mfma_i32_16x16x64_i8.
// Block = 4 waves (256 thr); wave tile 64co x 64px (1 output row) -> acc 64
// AGPR; launch_bounds(256,3) pins VGPR+AGPR <= 170 -> 3 waves/SIMD.
// Grid is 1D with an XCD-locality remap: the 5 co-tiles of one ptile map to
// ids {k, k+8, ..., k+32} -> same XCD (id%8 round-robin) and adjacent in
// dispatch time, so xq rows are fetched from LLC once and re-read from the
// XCD's L2 for the other 4 co-tiles (FETCH_SIZE ~117MB -> ~5x less).
// Inner loop: A fragments double-buffered across p, B fragment prefetched
// across i (explicit regs; VGPR 72->~100, still within the 3-wave budget),
// s_setprio(1) around each 4-MFMA cluster.
// ---------------------------------------------------------------------------
__global__ __launch_bounds__(256, 3) void conv_mfma_kernel(
    const char* __restrict__ xq, const char* __restrict__ wq2,
    const float* __restrict__ bi, const float* __restrict__ shift_p,
    float* __restrict__ out)
{
    __shared__ __attribute__((aligned(16))) char B_lds[2][25344]; // 6 rows x 66 x 64

    const int t  = threadIdx.x;
    const int id = blockIdx.x;           // 0..1279
    // id = (ptile&7) + 8*bx + 40*(ptile>>3)  -- invert:
    const int g  = id / 40;
    const int r  = id - g * 40;
    const int bx = r >> 3;               // co tile 0..4
    const int ptile = (g << 3) | (r & 7);

    const int co0 = bx * 64;
    const int b  = ptile >> 4;
    const int h0 = (ptile & 15) * 4;

    const int wave = t >> 6, lane = t & 63;
    const int quad = lane >> 4, l15 = lane & 15;

    const char* xbase = xq + ((size_t)(b * 66 + h0) * 66) * 320;

    v4i acc[4][4] = {};

    // prologue: stage c5=0 into buffer 0
    for (int c = t; c < 1584; c += 256) {
        const char* gp = xbase + (c >> 2) * 320 + ((c & 3) << 4);
        gload_lds16(gp, &B_lds[0][(c - lane) * 16]);
    }
    __syncthreads();

    for (int c5 = 0; c5 < 5; ++c5) {
        // issue next stage's DMA first (lands in the other buffer; drained by
        // the barrier AFTER this c5's compute -> fully overlapped)
        if (c5 < 4) {
            const int ci0 = (c5 + 1) * 64;
            char* dst = B_lds[(c5 + 1) & 1];
            for (int c = t; c < 1584; c += 256) {
                const char* gp = xbase + (c >> 2) * 320 + ci0 + ((c & 3) << 4);
                gload_lds16(gp, &dst[(c - lane) * 16]);
            }
        }

        const char* Bc = B_lds[c5 & 1];
        const char* wp = wq2 + (c5 * 20 + bx * 4) * 1024 + lane * 16;

        // A double-buffer: prefetch p+1's 4 fragments while p's MFMAs run.
        v4i areg[2][4];
#pragma unroll
        for (int cs = 0; cs < 4; ++cs)
            areg[0][cs] = *(const v4i*)(wp + 0 * 102400 + cs * 1024);

#pragma unroll
        for (int p = 0; p < 9; ++p) {
            const int dh = p / 3, dw = p - dh * 3;
            if (p < 8) {
#pragma unroll
                for (int cs = 0; cs < 4; ++cs)
                    areg[(p + 1) & 1][cs] =
                        *(const v4i*)(wp + (p + 1) * 102400 + cs * 1024);
            }
            const int prow = wave + dh;
            auto bread = [&](int i) -> v4i {
                const int col = i * 16 + l15 + dw;
                const int key = (col >> 1) & 3;
                return *(const v4i*)&Bc[(prow * 66 + col) * 64 +
                                        ((quad ^ key) << 4)];
            };
            v4i bf = bread(0);
#pragma unroll
            for (int i = 0; i < 4; ++i) {
                v4i bcur = bf;
                if (i < 3) bf = bread(i + 1);
                __builtin_amdgcn_s_setprio(1);
#pragma unroll
                for (int cs = 0; cs < 4; ++cs)
                    acc[cs][i] = mfma_i8(areg[p & 1][cs], bcur, acc[cs][i]);
                __builtin_amdgcn_s_setprio(0);
            }
        }
        __syncthreads();
    }

    // epilogue: y_shift = clip(rint(y*shift)); out = clip(y_shift + b_int8)
    const float shift = *shift_p;
    const int h = h0 + wave;
#pragma unroll
    for (int cs = 0; cs < 4; ++cs) {
#pragma unroll
        for (int reg = 0; reg < 4; ++reg) {
            const int co = co0 + cs * 16 + quad * 4 + reg;
            const float bv = bi[co];
            float* orow = out + (((size_t)(b * 320 + co) * 64) + h) * 64;
#pragma unroll
            for (int i = 0; i < 4; ++i) {
                float y  = (float)acc[cs][i][reg];
                float ys = clampf(rintf(y * shift), -QMAX, QMAX);
                orow[i * 16 + l15] = clampf(ys + bv, -QMAX, QMAX);
            }
        }
    }
}

extern "C" void kernel_launch(void* const* d_in, const int* in_sizes, int n_in,
                              void* d_out, int out_size, void* d_ws, size_t ws_size,
                              hipStream_t stream) {
    const float* x      = (const float*)d_in[0];
    const float* w      = (const float*)d_in[1];
    const float* bias   = (const float*)d_in[2];
    const float* step_x = (const float*)d_in[3];
    const float* step_w = (const float*)d_in[4];
    const float* step_b = (const float*)d_in[5];
    const float* shift  = (const float*)d_in[6];
    float* out = (float*)d_out;

    char*  xq  = (char*)d_ws;
    char*  wq2 = xq + XQ_BYTES;
    float* bi  = (float*)(wq2 + WQ_BYTES);

    fused_prep_kernel<<<4950, 256, 0, stream>>>(x, w, bias, step_x, step_w,
                                                step_b, shift, xq, wq2, bi);
    conv_mfma_kernel<<<1280, 256, 0, stream>>>(xq, wq2, bi, shift, out);
}